// Round 1
// baseline (209.358 us; speedup 1.0000x reference)
//
#include <hip/hip_runtime.h>

// InteractionBlock, MI355X fused implementation.
//
// Algebra: y = (out + (gathersum(out) @ W2 + b2)) @ W3 + b3
//            = out @ W3 + gathersum(out) @ (W2@W3) + (b2@W3 + b3)
// since gathersum is linear. Kernel 1 computes W23 = W2@W3 and
// bb = b2@W3 + b3 into workspace; kernel 2 does one fused pass:
// per grid point g (one wave, both batches), gather-sum 32 neighbor rows,
// then two independent 64x64 matvecs with weight columns held in VGPRs and
// row values broadcast via v_readlane (SGPR operand into v_fmac).

constexpr int A = 64;   // ao_vals
constexpr int K = 32;   // neighbors

__global__ void w23_kernel(const float* __restrict__ W2, const float* __restrict__ b2,
                           const float* __restrict__ W3, const float* __restrict__ b3,
                           float* __restrict__ W23, float* __restrict__ bb) {
  const int t = threadIdx.x;
  for (int e = t; e < A * A; e += blockDim.x) {
    const int i = e >> 6, j = e & 63;
    float acc = 0.f;
#pragma unroll
    for (int q = 0; q < A; ++q) acc = fmaf(W2[i * A + q], W3[q * A + j], acc);
    W23[e] = acc;
  }
  if (t < A) {
    float acc = b3[t];
#pragma unroll
    for (int q = 0; q < A; ++q) acc = fmaf(b2[q], W3[q * A + t], acc);
    bb[t] = acc;
  }
}

__device__ __forceinline__ float bcastf(float x, int l) {
  return __int_as_float(__builtin_amdgcn_readlane(__float_as_int(x), l));
}

// 256 threads = 4 waves/block; min 2 waves/EU caps VGPR at 256 (no spill of
// the 128-register weight-column arrays, still allows ~3 waves/SIMD actual).
__global__ __launch_bounds__(256, 2) void fused_kernel(
    const float* __restrict__ out, const int* __restrict__ nbr,
    const float* __restrict__ W23, const float* __restrict__ W3,
    const float* __restrict__ bb, float* __restrict__ y, const int G) {
  const int lane = threadIdx.x & 63;
  const int wid = (blockIdx.x * blockDim.x + threadIdx.x) >> 6;
  const int nw = (gridDim.x * blockDim.x) >> 6;

  // Lane j holds column j of each weight matrix (loaded once, reused over
  // the grid-stride loop; coalesced across lanes per i).
  float w23c[A], w3c[A];
#pragma unroll
  for (int i = 0; i < A; ++i) {
    w23c[i] = W23[i * A + lane];
    w3c[i]  = W3[i * A + lane];
  }
  const float bbv = bb[lane];
  const int GA = G * A;

  for (int g = wid; g < G; g += nw) {
    // lanes 0..31 hold the 32 neighbor indices for g (lanes 32..63 duplicate)
    const int idxv = nbr[g * K + (lane & (K - 1))];

    float m0 = 0.f, m1 = 0.f;
#pragma unroll
    for (int k = 0; k < K; ++k) {
      const int j = __builtin_amdgcn_readlane(idxv, k);  // wave-uniform
      const int jj = (j < G) ? j : 0;                    // clamp pad index
      const float sel = (j < G) ? 1.0f : 0.0f;           // scalar multiplier
      const float* p = out + jj * A;
      const float u0 = p[lane];        // batch 0: coalesced 256B row
      const float u1 = p[GA + lane];   // batch 1
      m0 = fmaf(u0, sel, m0);          // v_fmac with SGPR sel: 1 VALU op
      m1 = fmaf(u1, sel, m1);
    }

    const float o0 = out[g * A + lane];
    const float o1 = out[GA + g * A + lane];

    // y_b[lane] = bb[lane] + sum_i m_b[i]*W23[i][lane] + o_b[i]*W3[i][lane]
    // 4 independent FMA chains to cut dependency latency.
    float ya0 = bbv, yb0 = 0.f, ya1 = bbv, yb1 = 0.f;
#pragma unroll
    for (int i = 0; i < A; ++i) {
      ya0 = fmaf(bcastf(m0, i), w23c[i], ya0);
      yb0 = fmaf(bcastf(o0, i), w3c[i],  yb0);
      ya1 = fmaf(bcastf(m1, i), w23c[i], ya1);
      yb1 = fmaf(bcastf(o1, i), w3c[i],  yb1);
    }

    y[g * A + lane]      = ya0 + yb0;
    y[GA + g * A + lane] = ya1 + yb1;
  }
}

extern "C" void kernel_launch(void* const* d_in, const int* in_sizes, int n_in,
                              void* d_out, int out_size, void* d_ws, size_t ws_size,
                              hipStream_t stream) {
  const float* out = (const float*)d_in[0];
  const int*   nbr = (const int*)d_in[1];
  const float* W2  = (const float*)d_in[2];
  const float* b2  = (const float*)d_in[3];
  const float* W3  = (const float*)d_in[4];
  const float* b3  = (const float*)d_in[5];
  float* y = (float*)d_out;
  const int G = in_sizes[1] / K;

  float* W23 = (float*)d_ws;          // 64*64 floats
  float* bb  = W23 + A * A;           // 64 floats

  w23_kernel<<<1, 256, 0, stream>>>(W2, b2, W3, b3, W23, bb);
  fused_kernel<<<1024, 256, 0, stream>>>(out, nbr, W23, W3, bb, y, G);
}

// Round 2
// 190.260 us; speedup vs baseline: 1.1004x; 1.1004x over previous
//
#include <hip/hip_runtime.h>

// InteractionBlock, MI355X fused implementation, round 2.
//
// Algebra: y = (out + (gathersum(out) @ W2 + b2)) @ W3 + b3
//            = out @ W3 + gathersum(out) @ (W2@W3) + (b2@W3 + b3)
// (gathersum is linear). Kernel 1 (16 blocks) computes W23 = W2@W3 and
// bb = b2@W3 + b3. Kernel 2: one wave per grid point g, both batches.
// Weights live in LDS (interleaved rows -> ds_read2 pair, bank-conflict-free),
// NOT in VGPRs: R1 showed the allocator demotes 128-float register arrays
// (VGPR_Count=96 -> per-g global re-loads). Gather uses wave-uniform scalar
// base addresses (readlane -> SALU) and a uniform 0/1 multiplier for the
// zero-pad row (branch-free, 1 v_fmac per load).

constexpr int A = 64;   // ao_vals
constexpr int K = 32;   // neighbors

__global__ void w23_kernel(const float* __restrict__ W2, const float* __restrict__ b2,
                           const float* __restrict__ W3, const float* __restrict__ b3,
                           float* __restrict__ W23, float* __restrict__ bb) {
  // grid 16 x 256: one thread per output element of the 64x64 product.
  const int e = blockIdx.x * 256 + threadIdx.x;   // 0..4095
  const int i = e >> 6, j = e & 63;
  float acc = 0.f;
#pragma unroll
  for (int q = 0; q < A; ++q) acc = fmaf(W2[i * A + q], W3[q * A + j], acc);
  W23[e] = acc;
  if (blockIdx.x == 0 && threadIdx.x < A) {
    const int t = threadIdx.x;
    float b = b3[t];
#pragma unroll
    for (int q = 0; q < A; ++q) b = fmaf(b2[q], W3[q * A + t], b);
    bb[t] = b;
  }
}

__device__ __forceinline__ float bcastf(float x, int l) {
  return __int_as_float(__builtin_amdgcn_readlane(__float_as_int(x), l));
}

// 256 threads = 4 waves/block, one g per wave. launch_bounds(256,4) caps
// VGPR at 128: enough for gather state + 4 FMA chains, no spills, and
// 4 waves/SIMD (16 waves/CU) to hide gather latency. LDS 32KB/block ->
// 4 blocks/CU = 128KB <= 160KB, not the occupancy limiter.
__global__ __launch_bounds__(256, 4) void fused_kernel(
    const float* __restrict__ out, const int* __restrict__ nbr,
    const float* __restrict__ W23, const float* __restrict__ W3,
    const float* __restrict__ bb, float* __restrict__ y, const int G) {
  // Interleaved weight rows: WI[i*128 + j] = W23[i][j], WI[i*128+64+j] = W3[i][j].
  // Per-i reads WI[i*128+lane] / WI[i*128+64+lane]: bank = lane%32 -> 2-way (free),
  // and the pair is ds_read2-mergeable (offsets 0 and 256B from one base).
  __shared__ float WI[A * 128];
  const int tid = threadIdx.x;
  for (int e = tid; e < A * 128; e += 256) {
    const int i = e >> 7, c = e & 127;
    WI[e] = (c < A) ? W23[i * A + c] : W3[i * A + (c - A)];
  }
  __syncthreads();

  const int lane = tid & 63;
  const int g = (blockIdx.x * blockDim.x + tid) >> 6;   // one wave per g
  if (g >= G) return;

  const float bbv = bb[lane];
  const int GA = G * A;

  // residual-path row loads (independent of gather; issue early)
  const float o0 = out[g * A + lane];
  const float o1 = out[GA + g * A + lane];

  // lanes 0..31 hold the 32 neighbor indices (lanes 32..63 duplicate)
  const int idxv = nbr[g * K + (lane & (K - 1))];

  float m0 = 0.f, m1 = 0.f;
#pragma unroll
  for (int k = 0; k < K; ++k) {
    const int j = __builtin_amdgcn_readlane(idxv, k);  // wave-uniform -> SGPR
    const int jj = (j < G) ? j : 0;                    // clamp pad index (scalar)
    const float sel = (j < G) ? 1.0f : 0.0f;           // uniform multiplier
    const float* p = out + jj * A;                     // scalar base address
    const float u0 = p[lane];                          // coalesced 256B row
    const float u1 = p[GA + lane];
    m0 = fmaf(u0, sel, m0);                            // v_fmac, sel in SGPR
    m1 = fmaf(u1, sel, m1);
  }

  // y_b[lane] = bb + sum_i m_b[i]*W23[i][lane] + o_b[i]*W3[i][lane]
  float ya0 = bbv, yb0 = 0.f, ya1 = bbv, yb1 = 0.f;
#pragma unroll
  for (int i = 0; i < A; ++i) {
    const float w2c = WI[i * 128 + lane];
    const float w3c = WI[i * 128 + A + lane];
    ya0 = fmaf(bcastf(m0, i), w2c, ya0);
    ya1 = fmaf(bcastf(m1, i), w2c, ya1);
    yb0 = fmaf(bcastf(o0, i), w3c, yb0);
    yb1 = fmaf(bcastf(o1, i), w3c, yb1);
  }

  y[g * A + lane]      = ya0 + yb0;
  y[GA + g * A + lane] = ya1 + yb1;
}

extern "C" void kernel_launch(void* const* d_in, const int* in_sizes, int n_in,
                              void* d_out, int out_size, void* d_ws, size_t ws_size,
                              hipStream_t stream) {
  const float* out = (const float*)d_in[0];
  const int*   nbr = (const int*)d_in[1];
  const float* W2  = (const float*)d_in[2];
  const float* b2  = (const float*)d_in[3];
  const float* W3  = (const float*)d_in[4];
  const float* b3  = (const float*)d_in[5];
  float* y = (float*)d_out;
  const int G = in_sizes[1] / K;

  float* W23 = (float*)d_ws;          // 64*64 floats
  float* bb  = W23 + A * A;           // 64 floats

  w23_kernel<<<16, 256, 0, stream>>>(W2, b2, W3, b3, W23, bb);

  const int waves = G;                               // one wave per g
  const int blocks = (waves * A + 255) / 256;        // 64 threads per wave
  fused_kernel<<<blocks, 256, 0, stream>>>(out, nbr, W23, W3, bb, y, G);
}

// Round 3
// 168.130 us; speedup vs baseline: 1.2452x; 1.1316x over previous
//
#include <hip/hip_runtime.h>
#include <hip/hip_fp16.h>

// InteractionBlock, MI355X, round 3.
//
// Algebra: y = out @ W3 + gathersum(out) @ (W2@W3) + (b2@W3 + b3).
// R1/R2 showed the fused kernel pinned at FETCH_SIZE/dur ~= 3.3 TB/s over
// ~352 MB of L2-miss traffic (random 256B-row gather from a 25.6MB hot set)
// regardless of occupancy -> L2-miss-path throughput bound. R3 halves both
// bytes and requests: rows are packed fp16, both batches in ONE 256-B row
// ([G+1][64] half2; lanes 0..31 = batch0 elem pairs, 32..63 = batch1), with a
// materialized zero row at index G (no clamp in inner loop). Neighbor indices
// are loaded via uniform pointer (readfirstlane(g)) -> scalar s_loads.
// Accumulation stays fp32 (fp16 only on the wire): y error ~2e-3 << 0.125 tol.

constexpr int A = 64;   // ao_vals
constexpr int K = 32;   // neighbors

// ---- kernel 1: W23 = W2@W3, bb = b2@W3 + b3 (16 x 256, one elem/thread) ----
__global__ void w23_kernel(const float* __restrict__ W2, const float* __restrict__ b2,
                           const float* __restrict__ W3, const float* __restrict__ b3,
                           float* __restrict__ W23, float* __restrict__ bb) {
  const int e = blockIdx.x * 256 + threadIdx.x;   // 0..4095
  const int i = e >> 6, j = e & 63;
  float acc = 0.f;
#pragma unroll
  for (int q = 0; q < A; ++q) acc = fmaf(W2[i * A + q], W3[q * A + j], acc);
  W23[e] = acc;
  if (blockIdx.x == 0 && threadIdx.x < A) {
    const int t = threadIdx.x;
    float b = b3[t];
#pragma unroll
    for (int q = 0; q < A; ++q) b = fmaf(b2[q], W3[q * A + t], b);
    bb[t] = b;
  }
}

// ---- kernel 2: pack out (fp32 [2][G][64]) -> packed ([G+1][64] half2) ----
// dword c of row g: c<32 -> batch0 elements (2c,2c+1); else batch1 (2(c-32),..).
// Row G is the zero pad row (ws is poisoned 0xAA each launch; must rewrite).
__global__ void pack_kernel(const float2* __restrict__ out2,
                            __half2* __restrict__ packed, const int G) {
  const int d = blockIdx.x * 256 + threadIdx.x;
  const int total = (G + 1) * 64;
  if (d >= total) return;
  const int g = d >> 6, c = d & 63;
  float2 v = make_float2(0.f, 0.f);
  if (g < G) {
    const int b = c >> 5;
    v = out2[(size_t)b * (G * 32) + (size_t)g * 32 + (c & 31)];
  }
  packed[d] = __floats2half2_rn(v.x, v.y);
}

__device__ __forceinline__ float bcastf(float x, int l) {
  return __int_as_float(__builtin_amdgcn_readlane(__float_as_int(x), l));
}

// ---- kernel 3: fused gather-sum + both matvecs. One wave per g. ----
// LDS exactly 32 KB -> 5 blocks/CU (160 KB), launch_bounds(256,5) = 20 waves/CU.
__global__ __launch_bounds__(256, 5) void fused_kernel(
    const __half2* __restrict__ packed, const int* __restrict__ nbr,
    const float* __restrict__ W23, const float* __restrict__ W3,
    const float* __restrict__ bb, float* __restrict__ y, const int G) {
  // Interleaved weight columns: WI[i*128+lane] = W23[i][lane],
  // WI[i*128+64+lane] = W3[i][lane]  (pairs merge to ds_read2, conflict-free).
  __shared__ float WI[A * 128];
  const int tid = threadIdx.x;
  for (int e = tid; e < A * 128; e += 256) {
    const int i = e >> 7, c = e & 127;
    WI[e] = (c < A) ? W23[i * A + c] : W3[i * A + (c - A)];
  }
  __syncthreads();

  const int lane = tid & 63;
  // wave-uniform g in an SGPR -> uniform nbr pointer -> scalar s_loads
  const int g = __builtin_amdgcn_readfirstlane(blockIdx.x * 4 + (tid >> 6));
  if (g >= G) return;

  const int* np = nbr + g * K;

  // Gather-sum: one dword per lane per neighbor (one 256-B request per k).
  // Lane holds elements (2e,2e+1) of batch (lane>>5), e = lane&31.
  float mx = 0.f, my = 0.f;
#pragma unroll
  for (int k = 0; k < K; ++k) {
    const int j = np[k];                                   // uniform (s_load)
    const float2 u = __half22float2(packed[(size_t)j * 64 + lane]);
    mx += u.x; my += u.y;                                  // fp32 accumulate
  }
  // Residual row, same packed layout.
  const float2 o = __half22float2(packed[(size_t)g * 64 + lane]);
  const float bbv = bb[lane];

  // y_b[lane] = bb[lane] + sum_i m_b[i]*W23[i][lane] + o_b[i]*W3[i][lane].
  // Element i of batch0 lives in lane i>>1 (x: even i, y: odd i); batch1 at +32.
  float ya0 = bbv, yb0 = 0.f, ya1 = bbv, yb1 = 0.f;
#pragma unroll
  for (int i = 0; i < A; ++i) {
    const int s0 = i >> 1, s1 = 32 + (i >> 1);
    const float w2c = WI[i * 128 + lane];
    const float w3c = WI[i * 128 + A + lane];
    const float m0v = bcastf((i & 1) ? my : mx, s0);
    const float m1v = bcastf((i & 1) ? my : mx, s1);
    const float o0v = bcastf((i & 1) ? o.y : o.x, s0);
    const float o1v = bcastf((i & 1) ? o.y : o.x, s1);
    ya0 = fmaf(m0v, w2c, ya0);
    ya1 = fmaf(m1v, w2c, ya1);
    yb0 = fmaf(o0v, w3c, yb0);
    yb1 = fmaf(o1v, w3c, yb1);
  }

  const int GA = G * A;
  y[g * A + lane]      = ya0 + yb0;
  y[GA + g * A + lane] = ya1 + yb1;
}

extern "C" void kernel_launch(void* const* d_in, const int* in_sizes, int n_in,
                              void* d_out, int out_size, void* d_ws, size_t ws_size,
                              hipStream_t stream) {
  const float* out = (const float*)d_in[0];
  const int*   nbr = (const int*)d_in[1];
  const float* W2  = (const float*)d_in[2];
  const float* b2  = (const float*)d_in[3];
  const float* W3  = (const float*)d_in[4];
  const float* b3  = (const float*)d_in[5];
  float* y = (float*)d_out;
  const int G = in_sizes[1] / K;

  // Workspace layout: packed rows first (256-B rows), then W23, then bb.
  __half2* packed = (__half2*)d_ws;                       // (G+1)*64 half2
  const size_t packedBytes = (size_t)(G + 1) * 64 * sizeof(__half2);
  float* W23 = (float*)((char*)d_ws + packedBytes);       // 4096 floats
  float* bb  = W23 + A * A;                               // 64 floats

  w23_kernel<<<16, 256, 0, stream>>>(W2, b2, W3, b3, W23, bb);

  const int packTotal = (G + 1) * 64;
  pack_kernel<<<(packTotal + 255) / 256, 256, 0, stream>>>(
      (const float2*)out, packed, G);

  const int blocks = (G + 3) / 4;                         // one wave per g
  fused_kernel<<<blocks, 256, 0, stream>>>(packed, nbr, W23, W3, bb, y, G);
}

// Round 4
// 144.401 us; speedup vs baseline: 1.4498x; 1.1643x over previous
//
#include <hip/hip_runtime.h>
#include <hip/hip_fp16.h>

// InteractionBlock, MI355X, round 4.
//
// y = out @ W3 + gathersum(out) @ (W2@W3) + (b2@W3 + b3)
// R3 post-mortem: FETCH halved on cue (352->154 MB) but kernel flipped to
// VALU-issue-bound (VALUBusy 90%, ~1950 VALU instrs/wave) -- the readlane
// broadcast matvec costs ~2 VALU/MAC. R4: per block of 32 g's, the epilogue
// [64 rows x 128] @ [128 x 64] is done with mfma_f32_16x16x32_f16 (16 MFMA
// per wave replaces ~1300 VALU), and the gather accumulates with
// v_pk_add_f16 (1 VALU per neighbor row-load). LDS tiles padded to 272-B row
// stride -> every ds access <=2-way (free). Expect to return to the L2-miss
// path ceiling (~154 MB @ ~3.3 TB/s ~= 47 us).

constexpr int A  = 64;    // ao_vals
constexpr int K  = 32;    // neighbors
constexpr int GPB = 32;   // grid points per block (4 waves x 8)
constexpr int XS = 136;   // LDS row stride in halves (128 data + 8 pad)

typedef _Float16 f16x8 __attribute__((ext_vector_type(8)));
typedef float    f32x4 __attribute__((ext_vector_type(4)));

// ---- kernel 1: WTg[n][k] = (half) concat(W2@W3, W3)[k][n]  (n-major, 128/row)
//      bb = b2@W3 + b3 (fp32) ----
__global__ void wprep_kernel(const float* __restrict__ W2, const float* __restrict__ b2,
                             const float* __restrict__ W3, const float* __restrict__ b3,
                             __half* __restrict__ WTg, float* __restrict__ bb) {
  const int e = blockIdx.x * 256 + threadIdx.x;   // 0..4095
  const int n = e >> 6, k = e & 63;
  float acc = 0.f;
#pragma unroll
  for (int q = 0; q < A; ++q) acc = fmaf(W2[k * A + q], W3[q * A + n], acc);
  WTg[n * 128 + k]     = __float2half(acc);          // W23 part (K rows 0..63)
  WTg[n * 128 + A + k] = __float2half(W3[k * A + n]); // W3 part (K rows 64..127)
  if (blockIdx.x == 0 && threadIdx.x < A) {
    const int t = threadIdx.x;
    float b = b3[t];
#pragma unroll
    for (int q = 0; q < A; ++q) b = fmaf(b2[q], W3[q * A + t], b);
    bb[t] = b;
  }
}

// ---- kernel 2: pack out (fp32 [2][G][64]) -> packed ([G+1][64] half2) ----
// dword c of row g: c<32 -> batch0 element pair (2c,2c+1); else batch1.
// Row G is the materialized zero pad row (ws re-poisoned every launch).
__global__ void pack_kernel(const float2* __restrict__ out2,
                            __half2* __restrict__ packed, const int G) {
  const int d = blockIdx.x * 256 + threadIdx.x;
  const int total = (G + 1) * 64;
  if (d >= total) return;
  const int g = d >> 6, c = d & 63;
  float2 v = make_float2(0.f, 0.f);
  if (g < G) {
    const int b = c >> 5;
    v = out2[(size_t)b * (G * 32) + (size_t)g * 32 + (c & 31)];
  }
  packed[d] = __floats2half2_rn(v.x, v.y);
}

// ---- kernel 3: fused gather-sum + MFMA epilogue. 4 waves, 32 g per block ----
// LDS 34.8 KB -> 4 blocks/CU (16 waves/CU).
__global__ __launch_bounds__(256, 4) void fused_kernel(
    const __half2* __restrict__ packed, const int* __restrict__ nbr,
    const __half* __restrict__ WTg, const float* __restrict__ bb,
    float* __restrict__ y, const int G) {
  __shared__ __half X[64 * XS];   // rows: b*32+gl ; cols: [m(64) | o(64)]
  __shared__ __half WT[64 * XS];  // rows: n       ; cols: k (0..127)

  const int tid = threadIdx.x;

  // Stage WT (4096 dwords), coalesced; pad rows to 68 dwords.
  {
    const unsigned int* src = (const unsigned int*)WTg;
    unsigned int* dst = (unsigned int*)WT;
#pragma unroll
    for (int s = 0; s < 16; ++s) {
      const int d = s * 256 + tid;
      const int n = d >> 6, c = d & 63;
      dst[n * (XS / 2) + c] = src[d];
    }
  }

  const int lane = tid & 63;
  const int w = __builtin_amdgcn_readfirstlane(tid >> 6);  // wave id, SGPR
  const int gbase = blockIdx.x * GPB;
  const int gcount = min(GPB, G - gbase);
  const int e = lane & 31;              // element-pair index
  const int rb = (lane >> 5) * 32;      // row base: batch = lane>>5

  const __half2 z = __floats2half2_rn(0.f, 0.f);

  // Phase 1: each wave gather-sums 8 grid points (fp16 accumulate, 4 chains).
#pragma unroll
  for (int gg = 0; gg < 8; ++gg) {
    const int gl = w * 8 + gg;          // wave-uniform
    if (gl < gcount) {
      const int g = gbase + gl;
      const int* np = nbr + g * K;      // uniform pointer -> s_load indices
      __half2 m0 = z, m1 = z, m2 = z, m3 = z;
#pragma unroll
      for (int k = 0; k < K; k += 4) {
        const __half2 u0 = packed[(size_t)np[k]     * 64 + lane];
        const __half2 u1 = packed[(size_t)np[k + 1] * 64 + lane];
        const __half2 u2 = packed[(size_t)np[k + 2] * 64 + lane];
        const __half2 u3 = packed[(size_t)np[k + 3] * 64 + lane];
        m0 = __hadd2(m0, u0);
        m1 = __hadd2(m1, u1);
        m2 = __hadd2(m2, u2);
        m3 = __hadd2(m3, u3);
      }
      const __half2 m = __hadd2(__hadd2(m0, m1), __hadd2(m2, m3));
      const __half2 o = packed[(size_t)g * 64 + lane];   // residual row
      const int r = rb + gl;
      *(__half2*)&X[r * XS + 2 * e]     = m;
      *(__half2*)&X[r * XS + A + 2 * e] = o;
    }
  }
  __syncthreads();

  // Phase 2: Y[64x64] = X[64x128] @ WcatT^T, wave w does rows w*16..w*16+15.
  // A-frag: A[m=lane&15][k=quad*8+j]; B-frag: B[k=quad*8+j][n=lane&15];
  // C/D: col=lane&15, row=quad*4+reg (HW-verified, dtype-independent).
  const int quad = lane >> 4;
  const int mn = lane & 15;
  f32x4 acc0 = {0.f, 0.f, 0.f, 0.f};
  f32x4 acc1 = {0.f, 0.f, 0.f, 0.f};
  f32x4 acc2 = {0.f, 0.f, 0.f, 0.f};
  f32x4 acc3 = {0.f, 0.f, 0.f, 0.f};
#pragma unroll
  for (int kt = 0; kt < 4; ++kt) {
    const int ko = kt * 32 + quad * 8;
    const f16x8 a = *(const f16x8*)&X[(w * 16 + mn) * XS + ko];
    const f16x8 b0 = *(const f16x8*)&WT[(0 * 16 + mn) * XS + ko];
    acc0 = __builtin_amdgcn_mfma_f32_16x16x32_f16(a, b0, acc0, 0, 0, 0);
    const f16x8 b1 = *(const f16x8*)&WT[(1 * 16 + mn) * XS + ko];
    acc1 = __builtin_amdgcn_mfma_f32_16x16x32_f16(a, b1, acc1, 0, 0, 0);
    const f16x8 b2 = *(const f16x8*)&WT[(2 * 16 + mn) * XS + ko];
    acc2 = __builtin_amdgcn_mfma_f32_16x16x32_f16(a, b2, acc2, 0, 0, 0);
    const f16x8 b3 = *(const f16x8*)&WT[(3 * 16 + mn) * XS + ko];
    acc3 = __builtin_amdgcn_mfma_f32_16x16x32_f16(a, b3, acc3, 0, 0, 0);
  }

  // Store + bias. Row r = w*16 + quad*4 + reg -> (batch r>>5, gl = r&31).
  f32x4 accs[4] = {acc0, acc1, acc2, acc3};
#pragma unroll
  for (int nt = 0; nt < 4; ++nt) {
    const int col = nt * 16 + mn;
    const float bv = bb[col];
#pragma unroll
    for (int rg = 0; rg < 4; ++rg) {
      const int row = w * 16 + quad * 4 + rg;
      const int b = row >> 5, gl = row & 31;
      if (gl < gcount)
        y[((size_t)b * G + (gbase + gl)) * 64 + col] = accs[nt][rg] + bv;
    }
  }
}

extern "C" void kernel_launch(void* const* d_in, const int* in_sizes, int n_in,
                              void* d_out, int out_size, void* d_ws, size_t ws_size,
                              hipStream_t stream) {
  const float* out = (const float*)d_in[0];
  const int*   nbr = (const int*)d_in[1];
  const float* W2  = (const float*)d_in[2];
  const float* b2  = (const float*)d_in[3];
  const float* W3  = (const float*)d_in[4];
  const float* b3  = (const float*)d_in[5];
  float* y = (float*)d_out;
  const int G = in_sizes[1] / K;

  // ws: packed rows | WTg (fp16 128x64 transposed concat) | bb (fp32 64)
  __half2* packed = (__half2*)d_ws;                       // (G+1)*64 half2
  const size_t packedBytes = (size_t)(G + 1) * 64 * sizeof(__half2);
  __half* WTg = (__half*)((char*)d_ws + packedBytes);     // 8192 halves
  float* bb = (float*)((char*)d_ws + packedBytes + 8192 * sizeof(__half));

  wprep_kernel<<<16, 256, 0, stream>>>(W2, b2, W3, b3, WTg, bb);

  const int packTotal = (G + 1) * 64;
  pack_kernel<<<(packTotal + 255) / 256, 256, 0, stream>>>(
      (const float2*)out, packed, G);

  const int blocks = (G + GPB - 1) / GPB;
  fused_kernel<<<blocks, 256, 0, stream>>>(packed, nbr, WTg, bb, y, G);
}